// Round 2
// baseline (3221.127 us; speedup 1.0000x reference)
//
#include <hip/hip_runtime.h>

#define NNODES 50000
#define NEDGES 800000
#define DIM 128
#define NGRAPHS 256
#define RPB 16   // rows per block in conv gemm

// ---------------- scatter-add: agg[dst] += feat[src] over edges ----------------
// one edge handled by 32 threads, each doing a float4 gather + 4 atomic adds
__global__ void scatter_add_kernel(const float* __restrict__ feat,
                                   const int* __restrict__ src,
                                   const int* __restrict__ dst,
                                   float* __restrict__ agg) {
    int tid = blockIdx.x * blockDim.x + threadIdx.x;
    int e = tid >> 5;
    int q = tid & 31;
    if (e >= NEDGES) return;
    int s = src[e];
    int d = dst[e];
    float4 v = reinterpret_cast<const float4*>(feat)[(size_t)s * (DIM / 4) + q];
    float* ap = agg + (size_t)d * DIM + q * 4;
    atomicAdd(ap + 0, v.x);
    atomicAdd(ap + 1, v.y);
    atomicAdd(ap + 2, v.z);
    atomicAdd(ap + 3, v.w);
}

// ------------- fused GraphConv dense part: out = relu(agg@Wrel + b + x@Wroot) -------------
// block = 128 threads (one output column each), RPB rows staged in LDS.
// NOTE: xin/out may alias (layer 2 in-place): rows are fully staged to LDS
// before any write, and each block writes only its own rows. No __restrict__
// on xin/out.
__global__ void conv_gemm_kernel(const float* __restrict__ agg,
                                 const float* xin,
                                 const float* __restrict__ w_rel,
                                 const float* __restrict__ b_rel,
                                 const float* __restrict__ w_root,
                                 float* out) {
    __shared__ float a_lds[RPB][DIM];
    __shared__ float x_lds[RPB][DIM];
    const int row0 = blockIdx.x * RPB;
    const int c = threadIdx.x;  // 0..127

    // stage RPB rows of agg and xin (float4, coalesced)
    const float4* a4 = reinterpret_cast<const float4*>(agg + (size_t)row0 * DIM);
    const float4* x4 = reinterpret_cast<const float4*>(xin + (size_t)row0 * DIM);
    float4* al = reinterpret_cast<float4*>(&a_lds[0][0]);
    float4* xl = reinterpret_cast<float4*>(&x_lds[0][0]);
    #pragma unroll
    for (int i = 0; i < (RPB * DIM / 4) / 128; ++i) {
        int idx = i * 128 + c;
        al[idx] = a4[idx];
        xl[idx] = x4[idx];
    }
    __syncthreads();

    float acc[RPB];
    #pragma unroll
    for (int r = 0; r < RPB; ++r) acc[r] = 0.f;

    for (int k = 0; k < DIM; ++k) {
        float w1 = w_rel[k * DIM + c];
        float w2 = w_root[k * DIM + c];
        #pragma unroll
        for (int r = 0; r < RPB; ++r)
            acc[r] = fmaf(a_lds[r][k], w1, fmaf(x_lds[r][k], w2, acc[r]));
    }

    float bb = b_rel[c];
    #pragma unroll
    for (int r = 0; r < RPB; ++r) {
        float v = acc[r] + bb;
        out[(size_t)(row0 + r) * DIM + c] = v > 0.f ? v : 0.f;
    }
}

// ---------------- mean-pool accumulation ----------------
__global__ void pool_kernel(const float* __restrict__ h,
                            const int* __restrict__ batch,
                            float* __restrict__ sums,
                            float* __restrict__ counts) {
    int tid = blockIdx.x * blockDim.x + threadIdx.x;
    int n = tid >> 7;
    int f = tid & (DIM - 1);
    if (n >= NNODES) return;
    int g = batch[n];
    atomicAdd(&sums[(size_t)g * DIM + f], h[(size_t)n * DIM + f]);
    if (f == 0) atomicAdd(&counts[g], 1.0f);
}

// ---------------- final MLP: out[g] = relu(p@fc1+b1)@fc2 + b2 ----------------
__global__ void mlp_kernel(const float* __restrict__ sums,
                           const float* __restrict__ counts,
                           const float* __restrict__ fc1_w,
                           const float* __restrict__ fc1_b,
                           const float* __restrict__ fc2_w,
                           const float* __restrict__ fc2_b,
                           float* __restrict__ out) {
    __shared__ float p[DIM];
    __shared__ float red[DIM];
    int g = blockIdx.x;
    int c = threadIdx.x;  // 0..127
    float cnt = counts[g];
    cnt = cnt > 1.f ? cnt : 1.f;
    p[c] = sums[(size_t)g * DIM + c] / cnt;
    __syncthreads();
    float acc = fc1_b[c];
    for (int k = 0; k < DIM; ++k) acc = fmaf(p[k], fc1_w[k * DIM + c], acc);
    acc = acc > 0.f ? acc : 0.f;
    red[c] = acc * fc2_w[c];
    __syncthreads();
    #pragma unroll
    for (int s = 64; s > 0; s >>= 1) {
        if (c < s) red[c] += red[c + s];
        __syncthreads();
    }
    if (c == 0) out[g] = red[0] + fc2_b[0];
}

extern "C" void kernel_launch(void* const* d_in, const int* in_sizes, int n_in,
                              void* d_out, int out_size, void* d_ws, size_t ws_size,
                              hipStream_t stream) {
    const float* x       = (const float*)d_in[0];
    const int*   ei      = (const int*)d_in[1];
    const int*   batch   = (const int*)d_in[2];
    const float* w1_rel  = (const float*)d_in[3];
    const float* b1_rel  = (const float*)d_in[4];
    const float* w1_root = (const float*)d_in[5];
    const float* w2_rel  = (const float*)d_in[6];
    const float* b2_rel  = (const float*)d_in[7];
    const float* w2_root = (const float*)d_in[8];
    const float* fc1_w   = (const float*)d_in[9];
    const float* fc1_b   = (const float*)d_in[10];
    const float* fc2_w   = (const float*)d_in[11];
    const float* fc2_b   = (const float*)d_in[12];
    float* out = (float*)d_out;

    char* ws = (char*)d_ws;
    const size_t feat_bytes = (size_t)NNODES * DIM * sizeof(float);
    float* A      = (float*)ws;                       // aggregation buffer
    float* B      = (float*)(ws + feat_bytes);        // hidden activations
    float* sums   = (float*)(ws + 2 * feat_bytes);    // [NGRAPHS][DIM]
    float* counts = sums + (size_t)NGRAPHS * DIM;     // [NGRAPHS]

    const int* src = ei;           // edge_index[0]
    const int* dst = ei + NEDGES;  // edge_index[1]

    const int scatter_blocks = (NEDGES * 32) / 256;   // 100000
    const int gemm_blocks    = NNODES / RPB;          // 3125
    const int pool_blocks    = (NNODES * DIM) / 256;  // 25000

    // ---- layer 1 ----
    hipMemsetAsync(A, 0, feat_bytes, stream);
    hipMemsetAsync(sums, 0, ((size_t)NGRAPHS * DIM + NGRAPHS) * sizeof(float), stream);
    scatter_add_kernel<<<scatter_blocks, 256, 0, stream>>>(x, src, dst, A);
    conv_gemm_kernel<<<gemm_blocks, 128, 0, stream>>>(A, x, w1_rel, b1_rel, w1_root, B);

    // ---- layer 2 (in-place on B) ----
    hipMemsetAsync(A, 0, feat_bytes, stream);
    scatter_add_kernel<<<scatter_blocks, 256, 0, stream>>>(B, src, dst, A);
    conv_gemm_kernel<<<gemm_blocks, 128, 0, stream>>>(A, B, w2_rel, b2_rel, w2_root, B);

    // ---- pool + MLP ----
    pool_kernel<<<pool_blocks, 256, 0, stream>>>(B, batch, sums, counts);
    mlp_kernel<<<NGRAPHS, 128, 0, stream>>>(sums, counts, fc1_w, fc1_b, fc2_w, fc2_b, out);
}

// Round 3
// 690.022 us; speedup vs baseline: 4.6681x; 4.6681x over previous
//
#include <hip/hip_runtime.h>

#define NNODES 50000
#define NEDGES 800000
#define DIM 128
#define NGRAPHS 256
#define RPB 16          // rows per block in conv gemm
#define SCAN_THREADS 1024
#define CHUNK 49        // 1024*49 = 50176 >= NNODES
#define NPAD 50176      // padded node count for int arrays

// ---------------- edge histogram by dst ----------------
__global__ void hist_kernel(const int* __restrict__ dst, int* __restrict__ deg) {
    int e = blockIdx.x * 256 + threadIdx.x;
    if (e < NEDGES) atomicAdd(&deg[dst[e]], 1);
}

// ---------------- exclusive prefix scan over deg (single block) ----------------
__global__ void scan_kernel(const int* __restrict__ deg,
                            int* __restrict__ offs,
                            int* __restrict__ curs) {
    __shared__ int part[SCAN_THREADS];
    int t = threadIdx.x;
    int base = t * CHUNK;
    int sum = 0;
    for (int i = 0; i < CHUNK; ++i) {
        int idx = base + i;
        if (idx < NNODES) sum += deg[idx];
    }
    part[t] = sum;
    __syncthreads();
    for (int s = 1; s < SCAN_THREADS; s <<= 1) {
        int v = (t >= s) ? part[t - s] : 0;
        __syncthreads();
        part[t] += v;
        __syncthreads();
    }
    int run = (t == 0) ? 0 : part[t - 1];
    for (int i = 0; i < CHUNK; ++i) {
        int idx = base + i;
        if (idx < NNODES) {
            offs[idx] = run;
            curs[idx] = run;
            run += deg[idx];
        }
    }
    if (t == SCAN_THREADS - 1) offs[NNODES] = run;  // = NEDGES
}

// ---------------- bucket edges by dst: srcs_sorted[slot] = src[e] ----------------
__global__ void bucket_kernel(const int* __restrict__ src,
                              const int* __restrict__ dst,
                              int* __restrict__ curs,
                              int* __restrict__ srcs_sorted) {
    int e = blockIdx.x * 256 + threadIdx.x;
    if (e >= NEDGES) return;
    int pos = atomicAdd(&curs[dst[e]], 1);
    srcs_sorted[pos] = src[e];
}

// ---------------- gather-aggregate: agg[n] = sum over neighbors feat[s] ----------------
// 256 threads = 2 nodes per block, 128 cols each. No atomics, no zero-init.
__global__ void gather_agg_kernel(const float* __restrict__ feat,
                                  const int* __restrict__ offs,
                                  const int* __restrict__ srcs_sorted,
                                  float* __restrict__ agg) {
    int n = blockIdx.x * 2 + (threadIdx.x >> 7);
    int c = threadIdx.x & (DIM - 1);
    if (n >= NNODES) return;
    int beg = offs[n], end = offs[n + 1];
    float acc0 = 0.f, acc1 = 0.f;
    int i = beg;
    for (; i + 2 <= end; i += 2) {
        int s0 = srcs_sorted[i];
        int s1 = srcs_sorted[i + 1];
        acc0 += feat[(size_t)s0 * DIM + c];
        acc1 += feat[(size_t)s1 * DIM + c];
    }
    if (i < end) acc0 += feat[(size_t)srcs_sorted[i] * DIM + c];
    agg[(size_t)n * DIM + c] = acc0 + acc1;
}

// ------------- fused GraphConv dense part: out = relu(agg@Wrel + b + x@Wroot) -------------
// block = 128 threads (one output column each), RPB rows staged in LDS (float4).
// xin/out may alias (layer 2 in-place): rows fully staged to LDS before write.
__global__ void conv_gemm_kernel(const float* __restrict__ agg,
                                 const float* xin,
                                 const float* __restrict__ w_rel,
                                 const float* __restrict__ b_rel,
                                 const float* __restrict__ w_root,
                                 float* out) {
    __shared__ float4 a_lds[RPB][DIM / 4];
    __shared__ float4 x_lds[RPB][DIM / 4];
    const int row0 = blockIdx.x * RPB;
    const int c = threadIdx.x;  // 0..127

    const float4* a4 = reinterpret_cast<const float4*>(agg + (size_t)row0 * DIM);
    const float4* x4 = reinterpret_cast<const float4*>(xin + (size_t)row0 * DIM);
    float4* al = &a_lds[0][0];
    float4* xl = &x_lds[0][0];
    #pragma unroll
    for (int i = 0; i < (RPB * DIM / 4) / 128; ++i) {
        int idx = i * 128 + c;
        al[idx] = a4[idx];
        xl[idx] = x4[idx];
    }
    __syncthreads();

    float acc[RPB];
    #pragma unroll
    for (int r = 0; r < RPB; ++r) acc[r] = 0.f;

    for (int k0 = 0; k0 < DIM; k0 += 4) {
        float w1a = w_rel[(k0 + 0) * DIM + c];
        float w1b = w_rel[(k0 + 1) * DIM + c];
        float w1c = w_rel[(k0 + 2) * DIM + c];
        float w1d = w_rel[(k0 + 3) * DIM + c];
        float w2a = w_root[(k0 + 0) * DIM + c];
        float w2b = w_root[(k0 + 1) * DIM + c];
        float w2c = w_root[(k0 + 2) * DIM + c];
        float w2d = w_root[(k0 + 3) * DIM + c];
        #pragma unroll
        for (int r = 0; r < RPB; ++r) {
            float4 a = a_lds[r][k0 >> 2];
            float4 xx = x_lds[r][k0 >> 2];
            float t = acc[r];
            t = fmaf(a.x, w1a, t);
            t = fmaf(a.y, w1b, t);
            t = fmaf(a.z, w1c, t);
            t = fmaf(a.w, w1d, t);
            t = fmaf(xx.x, w2a, t);
            t = fmaf(xx.y, w2b, t);
            t = fmaf(xx.z, w2c, t);
            t = fmaf(xx.w, w2d, t);
            acc[r] = t;
        }
    }

    float bb = b_rel[c];
    #pragma unroll
    for (int r = 0; r < RPB; ++r) {
        float v = acc[r] + bb;
        out[(size_t)(row0 + r) * DIM + c] = v > 0.f ? v : 0.f;
    }
}

// ---------------- segmented mean-pool: batch is sorted, binary-search bounds ----------------
__global__ void pool_seg_kernel(const float* __restrict__ h,
                                const int* __restrict__ batch,
                                float* __restrict__ pooled) {
    int g = blockIdx.x;
    int c = threadIdx.x;  // 0..127
    int lo = 0, hi = NNODES;
    while (lo < hi) { int m = (lo + hi) >> 1; if (batch[m] < g) lo = m + 1; else hi = m; }
    int beg = lo;
    hi = NNODES;
    while (lo < hi) { int m = (lo + hi) >> 1; if (batch[m] < g + 1) lo = m + 1; else hi = m; }
    int end = lo;
    float acc = 0.f;
    for (int n = beg; n < end; ++n) acc += h[(size_t)n * DIM + c];
    float cnt = (float)(end - beg);
    pooled[(size_t)g * DIM + c] = acc / fmaxf(cnt, 1.f);
}

// ---------------- final MLP: out[g] = relu(p@fc1+b1)@fc2 + b2 ----------------
__global__ void mlp_kernel(const float* __restrict__ pooled,
                           const float* __restrict__ fc1_w,
                           const float* __restrict__ fc1_b,
                           const float* __restrict__ fc2_w,
                           const float* __restrict__ fc2_b,
                           float* __restrict__ out) {
    __shared__ float p[DIM];
    __shared__ float red[DIM];
    int g = blockIdx.x;
    int c = threadIdx.x;  // 0..127
    p[c] = pooled[(size_t)g * DIM + c];
    __syncthreads();
    float acc = fc1_b[c];
    for (int k = 0; k < DIM; ++k) acc = fmaf(p[k], fc1_w[k * DIM + c], acc);
    acc = acc > 0.f ? acc : 0.f;
    red[c] = acc * fc2_w[c];
    __syncthreads();
    #pragma unroll
    for (int s = 64; s > 0; s >>= 1) {
        if (c < s) red[c] += red[c + s];
        __syncthreads();
    }
    if (c == 0) out[g] = red[0] + fc2_b[0];
}

extern "C" void kernel_launch(void* const* d_in, const int* in_sizes, int n_in,
                              void* d_out, int out_size, void* d_ws, size_t ws_size,
                              hipStream_t stream) {
    const float* x       = (const float*)d_in[0];
    const int*   ei      = (const int*)d_in[1];
    const int*   batch   = (const int*)d_in[2];
    const float* w1_rel  = (const float*)d_in[3];
    const float* b1_rel  = (const float*)d_in[4];
    const float* w1_root = (const float*)d_in[5];
    const float* w2_rel  = (const float*)d_in[6];
    const float* b2_rel  = (const float*)d_in[7];
    const float* w2_root = (const float*)d_in[8];
    const float* fc1_w   = (const float*)d_in[9];
    const float* fc1_b   = (const float*)d_in[10];
    const float* fc2_w   = (const float*)d_in[11];
    const float* fc2_b   = (const float*)d_in[12];
    float* out = (float*)d_out;

    char* ws = (char*)d_ws;
    const size_t feat_bytes = (size_t)NNODES * DIM * sizeof(float);  // 25.6 MB
    float* A      = (float*)ws;                       // aggregation buffer
    float* B      = (float*)(ws + feat_bytes);        // hidden activations
    int*   deg    = (int*)(ws + 2 * feat_bytes);      // [NPAD]
    int*   offs   = deg + NPAD;                       // [NPAD] (uses NNODES+1)
    int*   curs   = offs + NPAD;                      // [NPAD]
    int*   srcs   = curs + NPAD;                      // [NEDGES]
    float* pooled = (float*)(srcs + NEDGES);          // [NGRAPHS][DIM]

    const int* src = ei;           // edge_index[0]
    const int* dst = ei + NEDGES;  // edge_index[1]

    const int edge_blocks = (NEDGES + 255) / 256;     // 3125
    const int gemm_blocks = NNODES / RPB;             // 3125
    const int agg_blocks  = (NNODES + 1) / 2;         // 25000

    // ---- build dst-sorted adjacency (once, reused by both layers) ----
    hipMemsetAsync(deg, 0, NPAD * sizeof(int), stream);
    hist_kernel<<<edge_blocks, 256, 0, stream>>>(dst, deg);
    scan_kernel<<<1, SCAN_THREADS, 0, stream>>>(deg, offs, curs);
    bucket_kernel<<<edge_blocks, 256, 0, stream>>>(src, dst, curs, srcs);

    // ---- layer 1 ----
    gather_agg_kernel<<<agg_blocks, 256, 0, stream>>>(x, offs, srcs, A);
    conv_gemm_kernel<<<gemm_blocks, 128, 0, stream>>>(A, x, w1_rel, b1_rel, w1_root, B);

    // ---- layer 2 (in-place on B) ----
    gather_agg_kernel<<<agg_blocks, 256, 0, stream>>>(B, offs, srcs, A);
    conv_gemm_kernel<<<gemm_blocks, 128, 0, stream>>>(A, B, w2_rel, b2_rel, w2_root, B);

    // ---- pool + MLP ----
    pool_seg_kernel<<<NGRAPHS, 128, 0, stream>>>(B, batch, pooled);
    mlp_kernel<<<NGRAPHS, 128, 0, stream>>>(pooled, fc1_w, fc1_b, fc2_w, fc2_b, out);
}

// Round 5
// 488.482 us; speedup vs baseline: 6.5942x; 1.4126x over previous
//
#include <hip/hip_runtime.h>

#define NNODES 50000
#define NEDGES 800000
#define DIM 128
#define NGRAPHS 256
#define RPB 16          // rows per block in conv gemm
#define NPAD 50176      // 196*256, padded node count for int arrays
#define SCAN_BLOCKS 196

// ---------------- edge histogram by dst ----------------
__global__ void hist_kernel(const int* __restrict__ dst, int* __restrict__ deg) {
    int e = blockIdx.x * 256 + threadIdx.x;
    if (e < NEDGES) atomicAdd(&deg[dst[e]], 1);
}

// ---------------- 3-phase exclusive scan over deg[NPAD] ----------------
// phase 1: per-block (256-elem) sums
__global__ void scan1_kernel(const int* __restrict__ deg, int* __restrict__ bsum) {
    __shared__ int s[256];
    int t = threadIdx.x;
    s[t] = deg[blockIdx.x * 256 + t];
    __syncthreads();
    #pragma unroll
    for (int d = 128; d > 0; d >>= 1) {
        if (t < d) s[t] += s[t + d];
        __syncthreads();
    }
    if (t == 0) bsum[blockIdx.x] = s[0];
}

// phase 2: exclusive scan of SCAN_BLOCKS block sums (single tiny block)
__global__ void scan2_kernel(int* __restrict__ bsum) {
    __shared__ int s[256];
    int t = threadIdx.x;
    int v = (t < SCAN_BLOCKS) ? bsum[t] : 0;
    s[t] = v;
    __syncthreads();
    #pragma unroll
    for (int d = 1; d < 256; d <<= 1) {
        int u = (t >= d) ? s[t - d] : 0;
        __syncthreads();
        s[t] += u;
        __syncthreads();
    }
    if (t < SCAN_BLOCKS) bsum[t] = (t == 0) ? 0 : s[t - 1];
}

// phase 3: per-block exclusive scan + block base -> offs, curs
__global__ void scan3_kernel(const int* __restrict__ deg,
                             const int* __restrict__ bsum,
                             int* __restrict__ offs,
                             int* __restrict__ curs) {
    __shared__ int s[256];
    int t = threadIdx.x;
    int idx = blockIdx.x * 256 + t;
    s[t] = deg[idx];
    __syncthreads();
    #pragma unroll
    for (int d = 1; d < 256; d <<= 1) {
        int u = (t >= d) ? s[t - d] : 0;
        __syncthreads();
        s[t] += u;
        __syncthreads();
    }
    int excl = ((t == 0) ? 0 : s[t - 1]) + bsum[blockIdx.x];
    if (idx <= NNODES) {
        offs[idx] = excl;
        curs[idx] = excl;
    }
}

// ---------------- bucket edges by dst: srcs_sorted[slot] = src[e] ----------------
__global__ void bucket_kernel(const int* __restrict__ src,
                              const int* __restrict__ dst,
                              int* __restrict__ curs,
                              int* __restrict__ srcs_sorted) {
    int e = blockIdx.x * 256 + threadIdx.x;
    if (e >= NEDGES) return;
    int pos = atomicAdd(&curs[dst[e]], 1);
    srcs_sorted[pos] = src[e];
}

// ---------------- gather-aggregate: agg[n] = sum over neighbors feat[s] ----------------
// 32 lanes per node (float4 each), 8 nodes per 256-thread block. No atomics.
__global__ void gather_agg_kernel(const float* __restrict__ feat,
                                  const int* __restrict__ offs,
                                  const int* __restrict__ srcs_sorted,
                                  float* __restrict__ agg) {
    int n = blockIdx.x * 8 + (threadIdx.x >> 5);
    int q = threadIdx.x & 31;
    if (n >= NNODES) return;
    int beg = offs[n], end = offs[n + 1];
    const float4* f4 = reinterpret_cast<const float4*>(feat);
    float4 a0 = {0.f, 0.f, 0.f, 0.f};
    float4 a1 = {0.f, 0.f, 0.f, 0.f};
    int i = beg;
    for (; i + 2 <= end; i += 2) {
        int s0 = srcs_sorted[i];
        int s1 = srcs_sorted[i + 1];
        float4 v0 = f4[(size_t)s0 * (DIM / 4) + q];
        float4 v1 = f4[(size_t)s1 * (DIM / 4) + q];
        a0.x += v0.x; a0.y += v0.y; a0.z += v0.z; a0.w += v0.w;
        a1.x += v1.x; a1.y += v1.y; a1.z += v1.z; a1.w += v1.w;
    }
    if (i < end) {
        float4 v = f4[(size_t)srcs_sorted[i] * (DIM / 4) + q];
        a0.x += v.x; a0.y += v.y; a0.z += v.z; a0.w += v.w;
    }
    float4 r = {a0.x + a1.x, a0.y + a1.y, a0.z + a1.z, a0.w + a1.w};
    reinterpret_cast<float4*>(agg)[(size_t)n * (DIM / 4) + q] = r;
}

// ------------- fused GraphConv dense part: out = relu(agg@Wrel + b + x@Wroot) -------------
// block = 128 threads (one output column each), RPB rows staged in LDS (float4).
// xin/out may alias (layer 2 in-place): rows fully staged to LDS before write.
__global__ void conv_gemm_kernel(const float* __restrict__ agg,
                                 const float* xin,
                                 const float* __restrict__ w_rel,
                                 const float* __restrict__ b_rel,
                                 const float* __restrict__ w_root,
                                 float* out) {
    __shared__ float4 a_lds[RPB][DIM / 4];
    __shared__ float4 x_lds[RPB][DIM / 4];
    const int row0 = blockIdx.x * RPB;
    const int c = threadIdx.x;  // 0..127

    const float4* a4 = reinterpret_cast<const float4*>(agg + (size_t)row0 * DIM);
    const float4* x4 = reinterpret_cast<const float4*>(xin + (size_t)row0 * DIM);
    float4* al = &a_lds[0][0];
    float4* xl = &x_lds[0][0];
    #pragma unroll
    for (int i = 0; i < (RPB * DIM / 4) / 128; ++i) {
        int idx = i * 128 + c;
        al[idx] = a4[idx];
        xl[idx] = x4[idx];
    }
    __syncthreads();

    float acc[RPB];
    #pragma unroll
    for (int r = 0; r < RPB; ++r) acc[r] = 0.f;

    for (int k0 = 0; k0 < DIM; k0 += 4) {
        float w1a = w_rel[(k0 + 0) * DIM + c];
        float w1b = w_rel[(k0 + 1) * DIM + c];
        float w1c = w_rel[(k0 + 2) * DIM + c];
        float w1d = w_rel[(k0 + 3) * DIM + c];
        float w2a = w_root[(k0 + 0) * DIM + c];
        float w2b = w_root[(k0 + 1) * DIM + c];
        float w2c = w_root[(k0 + 2) * DIM + c];
        float w2d = w_root[(k0 + 3) * DIM + c];
        #pragma unroll
        for (int r = 0; r < RPB; ++r) {
            float4 a = a_lds[r][k0 >> 2];
            float4 xx = x_lds[r][k0 >> 2];
            float t = acc[r];
            t = fmaf(a.x, w1a, t);
            t = fmaf(a.y, w1b, t);
            t = fmaf(a.z, w1c, t);
            t = fmaf(a.w, w1d, t);
            t = fmaf(xx.x, w2a, t);
            t = fmaf(xx.y, w2b, t);
            t = fmaf(xx.z, w2c, t);
            t = fmaf(xx.w, w2d, t);
            acc[r] = t;
        }
    }

    float bb = b_rel[c];
    #pragma unroll
    for (int r = 0; r < RPB; ++r) {
        float v = acc[r] + bb;
        out[(size_t)(row0 + r) * DIM + c] = v > 0.f ? v : 0.f;
    }
}

// ---------------- segmented mean-pool: batch is sorted, binary-search bounds ----------------
__global__ void pool_seg_kernel(const float* __restrict__ h,
                                const int* __restrict__ batch,
                                float* __restrict__ pooled) {
    int g = blockIdx.x;
    int c = threadIdx.x;  // 0..127
    int lo = 0, hi = NNODES;
    while (lo < hi) { int m = (lo + hi) >> 1; if (batch[m] < g) lo = m + 1; else hi = m; }
    int beg = lo;
    hi = NNODES;
    while (lo < hi) { int m = (lo + hi) >> 1; if (batch[m] < g + 1) lo = m + 1; else hi = m; }
    int end = lo;
    float acc0 = 0.f, acc1 = 0.f;
    int n = beg;
    for (; n + 2 <= end; n += 2) {
        acc0 += h[(size_t)n * DIM + c];
        acc1 += h[(size_t)(n + 1) * DIM + c];
    }
    if (n < end) acc0 += h[(size_t)n * DIM + c];
    float cnt = (float)(end - beg);
    pooled[(size_t)g * DIM + c] = (acc0 + acc1) / fmaxf(cnt, 1.f);
}

// ---------------- final MLP: out[g] = relu(p@fc1+b1)@fc2 + b2 ----------------
__global__ void mlp_kernel(const float* __restrict__ pooled,
                           const float* __restrict__ fc1_w,
                           const float* __restrict__ fc1_b,
                           const float* __restrict__ fc2_w,
                           const float* __restrict__ fc2_b,
                           float* __restrict__ out) {
    __shared__ float p[DIM];
    __shared__ float red[DIM];
    int g = blockIdx.x;
    int c = threadIdx.x;  // 0..127
    p[c] = pooled[(size_t)g * DIM + c];
    __syncthreads();
    float acc = fc1_b[c];
    for (int k = 0; k < DIM; ++k) acc = fmaf(p[k], fc1_w[k * DIM + c], acc);
    acc = acc > 0.f ? acc : 0.f;
    red[c] = acc * fc2_w[c];
    __syncthreads();
    #pragma unroll
    for (int s = 64; s > 0; s >>= 1) {
        if (c < s) red[c] += red[c + s];
        __syncthreads();
    }
    if (c == 0) out[g] = red[0] + fc2_b[0];
}

extern "C" void kernel_launch(void* const* d_in, const int* in_sizes, int n_in,
                              void* d_out, int out_size, void* d_ws, size_t ws_size,
                              hipStream_t stream) {
    const float* x       = (const float*)d_in[0];
    const int*   ei      = (const int*)d_in[1];
    const int*   batch   = (const int*)d_in[2];
    const float* w1_rel  = (const float*)d_in[3];
    const float* b1_rel  = (const float*)d_in[4];
    const float* w1_root = (const float*)d_in[5];
    const float* w2_rel  = (const float*)d_in[6];
    const float* b2_rel  = (const float*)d_in[7];
    const float* w2_root = (const float*)d_in[8];
    const float* fc1_w   = (const float*)d_in[9];
    const float* fc1_b   = (const float*)d_in[10];
    const float* fc2_w   = (const float*)d_in[11];
    const float* fc2_b   = (const float*)d_in[12];
    float* out = (float*)d_out;

    char* ws = (char*)d_ws;
    const size_t feat_bytes = (size_t)NNODES * DIM * sizeof(float);  // 25.6 MB
    float* A      = (float*)ws;                       // aggregation buffer
    float* B      = (float*)(ws + feat_bytes);        // hidden activations
    int*   deg    = (int*)(ws + 2 * feat_bytes);      // [NPAD]
    int*   offs   = deg + NPAD;                       // [NPAD] (uses NNODES+1)
    int*   curs   = offs + NPAD;                      // [NPAD]
    int*   bsum   = curs + NPAD;                      // [256]
    int*   srcs   = bsum + 256;                       // [NEDGES]
    float* pooled = (float*)(srcs + NEDGES);          // [NGRAPHS][DIM]

    const int* src = ei;           // edge_index[0]
    const int* dst = ei + NEDGES;  // edge_index[1]

    const int edge_blocks = (NEDGES + 255) / 256;     // 3125
    const int gemm_blocks = NNODES / RPB;             // 3125
    const int agg_blocks  = (NNODES + 7) / 8;         // 6250

    // ---- build dst-sorted adjacency (once, reused by both layers) ----
    hipMemsetAsync(deg, 0, NPAD * sizeof(int), stream);
    hist_kernel<<<edge_blocks, 256, 0, stream>>>(dst, deg);
    scan1_kernel<<<SCAN_BLOCKS, 256, 0, stream>>>(deg, bsum);
    scan2_kernel<<<1, 256, 0, stream>>>(bsum);
    scan3_kernel<<<SCAN_BLOCKS, 256, 0, stream>>>(deg, bsum, offs, curs);
    bucket_kernel<<<edge_blocks, 256, 0, stream>>>(src, dst, curs, srcs);

    // ---- layer 1 ----
    gather_agg_kernel<<<agg_blocks, 256, 0, stream>>>(x, offs, srcs, A);
    conv_gemm_kernel<<<gemm_blocks, 128, 0, stream>>>(A, x, w1_rel, b1_rel, w1_root, B);

    // ---- layer 2 (in-place on B) ----
    gather_agg_kernel<<<agg_blocks, 256, 0, stream>>>(B, offs, srcs, A);
    conv_gemm_kernel<<<gemm_blocks, 128, 0, stream>>>(A, B, w2_rel, b2_rel, w2_root, B);

    // ---- pool + MLP ----
    pool_seg_kernel<<<NGRAPHS, 128, 0, stream>>>(B, batch, pooled);
    mlp_kernel<<<NGRAPHS, 128, 0, stream>>>(pooled, fc1_w, fc1_b, fc2_w, fc2_b, out);
}

// Round 7
// 353.814 us; speedup vs baseline: 9.1040x; 1.3806x over previous
//
#include <hip/hip_runtime.h>

#define NNODES 50000
#define NEDGES 800000
#define DIM 128
#define NGRAPHS 256
#define NPAD 50176      // 196*256, padded node count for int arrays
#define SCAN_BLOCKS 196

typedef _Float16 half4_t __attribute__((ext_vector_type(4)));
typedef _Float16 half8_t __attribute__((ext_vector_type(8)));
typedef float f32x4 __attribute__((ext_vector_type(4)));

// ---------------- cast x (f32) -> f16, 8 elems/thread ----------------
__global__ void cast_x_kernel(const float* __restrict__ x, _Float16* __restrict__ xh) {
    int t = blockIdx.x * 256 + threadIdx.x;      // t < 800000
    const float4* x4 = reinterpret_cast<const float4*>(x);
    float4 a = x4[t * 2];
    float4 b = x4[t * 2 + 1];
    half8_t h;
    h[0] = (_Float16)a.x; h[1] = (_Float16)a.y; h[2] = (_Float16)a.z; h[3] = (_Float16)a.w;
    h[4] = (_Float16)b.x; h[5] = (_Float16)b.y; h[6] = (_Float16)b.z; h[7] = (_Float16)b.w;
    *reinterpret_cast<half8_t*>(&xh[(size_t)t * 8]) = h;
}

// ------- build combined transposed f16 weights: WT[c][k] (k<128: w_rel, else w_root) -------
__global__ void cast_w_kernel(const float* __restrict__ w1_rel, const float* __restrict__ w1_root,
                              const float* __restrict__ w2_rel, const float* __restrict__ w2_root,
                              _Float16* __restrict__ WT1, _Float16* __restrict__ WT2) {
    int t = blockIdx.x * 256 + threadIdx.x;      // t < 65536
    int layer = t >> 15;
    int r = t & 32767;
    int c = r >> 8;        // 0..127 output col
    int k = r & 255;       // 0..255 combined K
    const float* wr = layer ? w2_rel : w1_rel;
    const float* wo = layer ? w2_root : w1_root;
    float v = (k < 128) ? wr[k * DIM + c] : wo[(k - 128) * DIM + c];
    _Float16* dstp = layer ? WT2 : WT1;
    dstp[(size_t)c * 256 + k] = (_Float16)v;
}

// ---------------- edge histogram by dst ----------------
__global__ void hist_kernel(const int* __restrict__ dst, int* __restrict__ deg) {
    int e = blockIdx.x * 256 + threadIdx.x;
    if (e < NEDGES) atomicAdd(&deg[dst[e]], 1);
}

// ---------------- 3-phase exclusive scan over deg[NPAD] ----------------
__global__ void scan1_kernel(const int* __restrict__ deg, int* __restrict__ bsum) {
    __shared__ int s[256];
    int t = threadIdx.x;
    s[t] = deg[blockIdx.x * 256 + t];
    __syncthreads();
    #pragma unroll
    for (int d = 128; d > 0; d >>= 1) {
        if (t < d) s[t] += s[t + d];
        __syncthreads();
    }
    if (t == 0) bsum[blockIdx.x] = s[0];
}

__global__ void scan2_kernel(int* __restrict__ bsum) {
    __shared__ int s[256];
    int t = threadIdx.x;
    int v = (t < SCAN_BLOCKS) ? bsum[t] : 0;
    s[t] = v;
    __syncthreads();
    #pragma unroll
    for (int d = 1; d < 256; d <<= 1) {
        int u = (t >= d) ? s[t - d] : 0;
        __syncthreads();
        s[t] += u;
        __syncthreads();
    }
    if (t < SCAN_BLOCKS) bsum[t] = (t == 0) ? 0 : s[t - 1];
}

__global__ void scan3_kernel(const int* __restrict__ deg,
                             const int* __restrict__ bsum,
                             int* __restrict__ offs,
                             int* __restrict__ curs) {
    __shared__ int s[256];
    int t = threadIdx.x;
    int idx = blockIdx.x * 256 + t;
    s[t] = deg[idx];
    __syncthreads();
    #pragma unroll
    for (int d = 1; d < 256; d <<= 1) {
        int u = (t >= d) ? s[t - d] : 0;
        __syncthreads();
        s[t] += u;
        __syncthreads();
    }
    int excl = ((t == 0) ? 0 : s[t - 1]) + bsum[blockIdx.x];
    if (idx <= NNODES) {
        offs[idx] = excl;
        curs[idx] = excl;
    }
}

// ---------------- bucket edges by dst ----------------
__global__ void bucket_kernel(const int* __restrict__ src,
                              const int* __restrict__ dst,
                              int* __restrict__ curs,
                              int* __restrict__ srcs_sorted) {
    int e = blockIdx.x * 256 + threadIdx.x;
    if (e >= NEDGES) return;
    int pos = atomicAdd(&curs[dst[e]], 1);
    srcs_sorted[pos] = src[e];
}

// ---------------- gather-aggregate (f16 in, f16 out, f32 accum) ----------------
// 32 lanes per node (half4 = 8B each), 8 nodes per 256-thread block.
__global__ void gather_agg_kernel(const _Float16* __restrict__ feat,
                                  const int* __restrict__ offs,
                                  const int* __restrict__ srcs_sorted,
                                  _Float16* __restrict__ agg) {
    int n = blockIdx.x * 8 + (threadIdx.x >> 5);
    int q = threadIdx.x & 31;
    if (n >= NNODES) return;
    int beg = offs[n], end = offs[n + 1];
    float4 a0 = {0.f, 0.f, 0.f, 0.f};
    float4 a1 = {0.f, 0.f, 0.f, 0.f};
    int i = beg;
    for (; i + 2 <= end; i += 2) {
        int s0 = srcs_sorted[i];
        int s1 = srcs_sorted[i + 1];
        half4_t v0 = *reinterpret_cast<const half4_t*>(&feat[(size_t)s0 * DIM + q * 4]);
        half4_t v1 = *reinterpret_cast<const half4_t*>(&feat[(size_t)s1 * DIM + q * 4]);
        a0.x += (float)v0[0]; a0.y += (float)v0[1]; a0.z += (float)v0[2]; a0.w += (float)v0[3];
        a1.x += (float)v1[0]; a1.y += (float)v1[1]; a1.z += (float)v1[2]; a1.w += (float)v1[3];
    }
    if (i < end) {
        half4_t v = *reinterpret_cast<const half4_t*>(&feat[(size_t)srcs_sorted[i] * DIM + q * 4]);
        a0.x += (float)v[0]; a0.y += (float)v[1]; a0.z += (float)v[2]; a0.w += (float)v[3];
    }
    half4_t r;
    r[0] = (_Float16)(a0.x + a1.x);
    r[1] = (_Float16)(a0.y + a1.y);
    r[2] = (_Float16)(a0.z + a1.z);
    r[3] = (_Float16)(a0.w + a1.w);
    *reinterpret_cast<half4_t*>(&agg[(size_t)n * DIM + q * 4]) = r;
}

// ------------- GraphConv dense part via fp16 MFMA -------------
// out = relu([Ah|Xh] @ WT^T + b), K=256 combined. Block = 4 waves = 128 rows.
// Per wave: 32 rows x 128 cols = 2 Msub x 8 Ntiles of 16x16x32 MFMA, f32 accum.
// No LDS: A/B frags via L1/L2. Xh/outh may alias (layer2 in-place): each block
// reads only its own rows and all reads precede its writes.
__global__ __launch_bounds__(256) void conv_mfma_kernel(
        const _Float16* __restrict__ Ah,
        const _Float16* Xh,
        const _Float16* __restrict__ WT,   // [128 cols][256 k]
        const float* __restrict__ bias,    // [128]
        _Float16* outh) {
    const int wave = threadIdx.x >> 6;
    const int lane = threadIdx.x & 63;
    const int row0 = blockIdx.x * 128 + wave * 32;
    const int rA = lane & 15;
    const int kg = lane >> 4;          // 0..3, k-group of 8

    f32x4 acc[2][8];
    #pragma unroll
    for (int m = 0; m < 2; ++m)
        #pragma unroll
        for (int nt = 0; nt < 8; ++nt)
            acc[m][nt] = (f32x4){0.f, 0.f, 0.f, 0.f};

    int ra0 = row0 + rA;        if (ra0 > NNODES - 1) ra0 = NNODES - 1;
    int ra1 = row0 + 16 + rA;   if (ra1 > NNODES - 1) ra1 = NNODES - 1;

    #pragma unroll
    for (int ks = 0; ks < 8; ++ks) {
        const _Float16* srcb = (ks < 4) ? Ah : Xh;
        const int klocal = (ks & 3) * 32 + kg * 8;
        half8_t a0 = *reinterpret_cast<const half8_t*>(&srcb[(size_t)ra0 * DIM + klocal]);
        half8_t a1 = *reinterpret_cast<const half8_t*>(&srcb[(size_t)ra1 * DIM + klocal]);
        const int kglob = ks * 32 + kg * 8;
        #pragma unroll
        for (int nt = 0; nt < 8; ++nt) {
            half8_t b = *reinterpret_cast<const half8_t*>(&WT[(size_t)(nt * 16 + rA) * 256 + kglob]);
            acc[0][nt] = __builtin_amdgcn_mfma_f32_16x16x32_f16(a0, b, acc[0][nt], 0, 0, 0);
            acc[1][nt] = __builtin_amdgcn_mfma_f32_16x16x32_f16(a1, b, acc[1][nt], 0, 0, 0);
        }
    }

    // C/D layout (HW-verified): col = lane&15, row = (lane>>4)*4 + reg
    const int ccol = lane & 15;
    const int crow4 = (lane >> 4) * 4;
    #pragma unroll
    for (int m = 0; m < 2; ++m) {
        #pragma unroll
        for (int nt = 0; nt < 8; ++nt) {
            float bb = bias[nt * 16 + ccol];
            #pragma unroll
            for (int r = 0; r < 4; ++r) {
                int row = row0 + m * 16 + crow4 + r;
                if (row < NNODES) {
                    float v = acc[m][nt][r] + bb;
                    outh[(size_t)row * DIM + nt * 16 + ccol] = (_Float16)(v > 0.f ? v : 0.f);
                }
            }
        }
    }
}

// ---------------- segmented mean-pool (f16 in): batch sorted, binary-search ----------------
__global__ void pool_seg_kernel(const _Float16* __restrict__ h,
                                const int* __restrict__ batch,
                                float* __restrict__ pooled) {
    int g = blockIdx.x;
    int c = threadIdx.x;  // 0..127
    int lo = 0, hi = NNODES;
    while (lo < hi) { int m = (lo + hi) >> 1; if (batch[m] < g) lo = m + 1; else hi = m; }
    int beg = lo;
    hi = NNODES;
    while (lo < hi) { int m = (lo + hi) >> 1; if (batch[m] < g + 1) lo = m + 1; else hi = m; }
    int end = lo;
    float acc0 = 0.f, acc1 = 0.f;
    int n = beg;
    for (; n + 2 <= end; n += 2) {
        acc0 += (float)h[(size_t)n * DIM + c];
        acc1 += (float)h[(size_t)(n + 1) * DIM + c];
    }
    if (n < end) acc0 += (float)h[(size_t)n * DIM + c];
    float cnt = (float)(end - beg);
    pooled[(size_t)g * DIM + c] = (acc0 + acc1) / fmaxf(cnt, 1.f);
}

// ---------------- final MLP (f32): out[g] = relu(p@fc1+b1)@fc2 + b2 ----------------
__global__ void mlp_kernel(const float* __restrict__ pooled,
                           const float* __restrict__ fc1_w,
                           const float* __restrict__ fc1_b,
                           const float* __restrict__ fc2_w,
                           const float* __restrict__ fc2_b,
                           float* __restrict__ out) {
    __shared__ float p[DIM];
    __shared__ float red[DIM];
    int g = blockIdx.x;
    int c = threadIdx.x;  // 0..127
    p[c] = pooled[(size_t)g * DIM + c];
    __syncthreads();
    float acc = fc1_b[c];
    for (int k = 0; k < DIM; ++k) acc = fmaf(p[k], fc1_w[k * DIM + c], acc);
    acc = acc > 0.f ? acc : 0.f;
    red[c] = acc * fc2_w[c];
    __syncthreads();
    #pragma unroll
    for (int s = 64; s > 0; s >>= 1) {
        if (c < s) red[c] += red[c + s];
        __syncthreads();
    }
    if (c == 0) out[g] = red[0] + fc2_b[0];
}

extern "C" void kernel_launch(void* const* d_in, const int* in_sizes, int n_in,
                              void* d_out, int out_size, void* d_ws, size_t ws_size,
                              hipStream_t stream) {
    const float* x       = (const float*)d_in[0];
    const int*   ei      = (const int*)d_in[1];
    const int*   batch   = (const int*)d_in[2];
    const float* w1_rel  = (const float*)d_in[3];
    const float* b1_rel  = (const float*)d_in[4];
    const float* w1_root = (const float*)d_in[5];
    const float* w2_rel  = (const float*)d_in[6];
    const float* b2_rel  = (const float*)d_in[7];
    const float* w2_root = (const float*)d_in[8];
    const float* fc1_w   = (const float*)d_in[9];
    const float* fc1_b   = (const float*)d_in[10];
    const float* fc2_w   = (const float*)d_in[11];
    const float* fc2_b   = (const float*)d_in[12];
    float* out = (float*)d_out;

    char* ws = (char*)d_ws;
    const size_t feath_bytes = (size_t)NNODES * DIM * sizeof(_Float16);  // 12.8 MB
    _Float16* Ah  = (_Float16*)ws;                                   // agg buffer (f16)
    _Float16* Hh  = (_Float16*)(ws + feath_bytes);                   // activations (f16)
    _Float16* xh  = (_Float16*)(ws + 2 * feath_bytes);               // x cast (f16)
    _Float16* WT1 = (_Float16*)(ws + 3 * feath_bytes);               // [128][256] f16
    _Float16* WT2 = WT1 + 128 * 256;
    int*   deg    = (int*)(WT2 + 128 * 256);       // [NPAD]
    int*   offs   = deg + NPAD;                    // [NPAD]
    int*   curs   = offs + NPAD;                   // [NPAD]
    int*   bsum   = curs + NPAD;                   // [256]
    int*   srcs   = bsum + 256;                    // [NEDGES]
    float* pooled = (float*)(srcs + NEDGES);       // [NGRAPHS][DIM]

    const int* src = ei;           // edge_index[0]
    const int* dst = ei + NEDGES;  // edge_index[1]

    const int edge_blocks = (NEDGES + 255) / 256;   // 3125
    const int conv_blocks = (NNODES + 127) / 128;   // 391
    const int agg_blocks  = (NNODES + 7) / 8;       // 6250

    // ---- casts ----
    cast_x_kernel<<<(NNODES * DIM / 8) / 256, 256, 0, stream>>>(x, xh);
    cast_w_kernel<<<256, 256, 0, stream>>>(w1_rel, w1_root, w2_rel, w2_root, WT1, WT2);

    // ---- build dst-sorted adjacency (once, reused by both layers) ----
    hipMemsetAsync(deg, 0, NPAD * sizeof(int), stream);
    hist_kernel<<<edge_blocks, 256, 0, stream>>>(dst, deg);
    scan1_kernel<<<SCAN_BLOCKS, 256, 0, stream>>>(deg, bsum);
    scan2_kernel<<<1, 256, 0, stream>>>(bsum);
    scan3_kernel<<<SCAN_BLOCKS, 256, 0, stream>>>(deg, bsum, offs, curs);
    bucket_kernel<<<edge_blocks, 256, 0, stream>>>(src, dst, curs, srcs);

    // ---- layer 1 ----
    gather_agg_kernel<<<agg_blocks, 256, 0, stream>>>(xh, offs, srcs, Ah);
    conv_mfma_kernel<<<conv_blocks, 256, 0, stream>>>(Ah, xh, WT1, b1_rel, Hh);

    // ---- layer 2 (in-place on Hh) ----
    gather_agg_kernel<<<agg_blocks, 256, 0, stream>>>(Hh, offs, srcs, Ah);
    conv_mfma_kernel<<<conv_blocks, 256, 0, stream>>>(Ah, Hh, WT2, b2_rel, Hh);

    // ---- pool + MLP ----
    pool_seg_kernel<<<NGRAPHS, 128, 0, stream>>>(Hh, batch, pooled);
    mlp_kernel<<<NGRAPHS, 128, 0, stream>>>(pooled, fc1_w, fc1_b, fc2_w, fc2_b, out);
}

// Round 10
// 346.677 us; speedup vs baseline: 9.2914x; 1.0206x over previous
//
#include <hip/hip_runtime.h>

#define NNODES 50000
#define NEDGES 800000
#define DIM 128
#define NGRAPHS 256
#define NPAD 50176      // 196*256, padded node count for int arrays
#define SCAN_BLOCKS 196

typedef _Float16 half4_t __attribute__((ext_vector_type(4)));
typedef _Float16 half8_t __attribute__((ext_vector_type(8)));
typedef float f32x4 __attribute__((ext_vector_type(4)));

// ---------------- cast x (f32) -> f16, 8 elems/thread ----------------
__global__ void cast_x_kernel(const float* __restrict__ x, _Float16* __restrict__ xh) {
    int t = blockIdx.x * 256 + threadIdx.x;      // t < 800000
    const float4* x4 = reinterpret_cast<const float4*>(x);
    float4 a = x4[t * 2];
    float4 b = x4[t * 2 + 1];
    half8_t h;
    h[0] = (_Float16)a.x; h[1] = (_Float16)a.y; h[2] = (_Float16)a.z; h[3] = (_Float16)a.w;
    h[4] = (_Float16)b.x; h[5] = (_Float16)b.y; h[6] = (_Float16)b.z; h[7] = (_Float16)b.w;
    *reinterpret_cast<half8_t*>(&xh[(size_t)t * 8]) = h;
}

// ------- build combined transposed f16 weights: WT[c][k] (k<128: w_rel, else w_root) -------
__global__ void cast_w_kernel(const float* __restrict__ w1_rel, const float* __restrict__ w1_root,
                              const float* __restrict__ w2_rel, const float* __restrict__ w2_root,
                              _Float16* __restrict__ WT1, _Float16* __restrict__ WT2) {
    int t = blockIdx.x * 256 + threadIdx.x;      // t < 65536
    int layer = t >> 15;
    int r = t & 32767;
    int c = r >> 8;        // 0..127 output col
    int k = r & 255;       // 0..255 combined K
    const float* wr = layer ? w2_rel : w1_rel;
    const float* wo = layer ? w2_root : w1_root;
    float v = (k < 128) ? wr[k * DIM + c] : wo[(k - 128) * DIM + c];
    _Float16* dstp = layer ? WT2 : WT1;
    dstp[(size_t)c * 256 + k] = (_Float16)v;
}

// ---------------- edge histogram by dst ----------------
__global__ void hist_kernel(const int* __restrict__ dst, int* __restrict__ deg) {
    int e = blockIdx.x * 256 + threadIdx.x;
    if (e < NEDGES) atomicAdd(&deg[dst[e]], 1);
}

// ---------------- 3-phase exclusive scan over deg[NPAD] ----------------
__global__ void scan1_kernel(const int* __restrict__ deg, int* __restrict__ bsum) {
    __shared__ int s[256];
    int t = threadIdx.x;
    s[t] = deg[blockIdx.x * 256 + t];
    __syncthreads();
    #pragma unroll
    for (int d = 128; d > 0; d >>= 1) {
        if (t < d) s[t] += s[t + d];
        __syncthreads();
    }
    if (t == 0) bsum[blockIdx.x] = s[0];
}

__global__ void scan2_kernel(int* __restrict__ bsum) {
    __shared__ int s[256];
    int t = threadIdx.x;
    int v = (t < SCAN_BLOCKS) ? bsum[t] : 0;
    s[t] = v;
    __syncthreads();
    #pragma unroll
    for (int d = 1; d < 256; d <<= 1) {
        int u = (t >= d) ? s[t - d] : 0;
        __syncthreads();
        s[t] += u;
        __syncthreads();
    }
    if (t < SCAN_BLOCKS) bsum[t] = (t == 0) ? 0 : s[t - 1];
}

__global__ void scan3_kernel(const int* __restrict__ deg,
                             const int* __restrict__ bsum,
                             int* __restrict__ offs,
                             int* __restrict__ curs) {
    __shared__ int s[256];
    int t = threadIdx.x;
    int idx = blockIdx.x * 256 + t;
    s[t] = deg[idx];
    __syncthreads();
    #pragma unroll
    for (int d = 1; d < 256; d <<= 1) {
        int u = (t >= d) ? s[t - d] : 0;
        __syncthreads();
        s[t] += u;
        __syncthreads();
    }
    int excl = ((t == 0) ? 0 : s[t - 1]) + bsum[blockIdx.x];
    if (idx <= NNODES) {
        offs[idx] = excl;
        curs[idx] = excl;
    }
}

// ---------------- bucket edges by dst (nontemporal scatter store) ----------------
__global__ void bucket_kernel(const int* __restrict__ src,
                              const int* __restrict__ dst,
                              int* __restrict__ curs,
                              int* __restrict__ srcs_sorted) {
    int e = blockIdx.x * 256 + threadIdx.x;
    if (e >= NEDGES) return;
    int pos = atomicAdd(&curs[dst[e]], 1);
    __builtin_nontemporal_store(src[e], &srcs_sorted[pos]);
}

// ---------------- gather-aggregate (f16 in, f16 out, f32 accum) ----------------
// 16 lanes per node (half8 = 16B each), 16 nodes per 256-thread block.
// 4-deep neighbor unroll for MLP-level ILP. No atomics.
__global__ void gather_agg_kernel(const _Float16* __restrict__ feat,
                                  const int* __restrict__ offs,
                                  const int* __restrict__ srcs_sorted,
                                  _Float16* __restrict__ agg) {
    int n = blockIdx.x * 16 + (threadIdx.x >> 4);
    int q = threadIdx.x & 15;
    if (n >= NNODES) return;
    int beg = offs[n], end = offs[n + 1];
    float a0[8] = {0.f, 0.f, 0.f, 0.f, 0.f, 0.f, 0.f, 0.f};
    float a1[8] = {0.f, 0.f, 0.f, 0.f, 0.f, 0.f, 0.f, 0.f};
    int i = beg;
    for (; i + 4 <= end; i += 4) {
        int s0 = srcs_sorted[i + 0];
        int s1 = srcs_sorted[i + 1];
        int s2 = srcs_sorted[i + 2];
        int s3 = srcs_sorted[i + 3];
        half8_t v0 = *reinterpret_cast<const half8_t*>(&feat[(size_t)s0 * DIM + q * 8]);
        half8_t v1 = *reinterpret_cast<const half8_t*>(&feat[(size_t)s1 * DIM + q * 8]);
        half8_t v2 = *reinterpret_cast<const half8_t*>(&feat[(size_t)s2 * DIM + q * 8]);
        half8_t v3 = *reinterpret_cast<const half8_t*>(&feat[(size_t)s3 * DIM + q * 8]);
        #pragma unroll
        for (int j = 0; j < 8; ++j) {
            a0[j] += (float)v0[j] + (float)v1[j];
            a1[j] += (float)v2[j] + (float)v3[j];
        }
    }
    for (; i < end; ++i) {
        half8_t v = *reinterpret_cast<const half8_t*>(&feat[(size_t)srcs_sorted[i] * DIM + q * 8]);
        #pragma unroll
        for (int j = 0; j < 8; ++j) a0[j] += (float)v[j];
    }
    half8_t r;
    #pragma unroll
    for (int j = 0; j < 8; ++j) r[j] = (_Float16)(a0[j] + a1[j]);
    *reinterpret_cast<half8_t*>(&agg[(size_t)n * DIM + q * 8]) = r;
}

// ------------- GraphConv dense part via fp16 MFMA -------------
// out = relu([Ah|Xh] @ WT^T + b), K=256 combined. Block = 4 waves = 128 rows.
// Per wave: 32 rows x 128 cols = 2 Msub x 8 Ntiles of 16x16x32 MFMA, f32 accum.
// No LDS: A/B frags via L1/L2. Xh/outh may alias (layer2 in-place): each block
// reads only its own rows and all reads precede its writes.
__global__ __launch_bounds__(256) void conv_mfma_kernel(
        const _Float16* __restrict__ Ah,
        const _Float16* Xh,
        const _Float16* __restrict__ WT,   // [128 cols][256 k]
        const float* __restrict__ bias,    // [128]
        _Float16* outh) {
    const int wave = threadIdx.x >> 6;
    const int lane = threadIdx.x & 63;
    const int row0 = blockIdx.x * 128 + wave * 32;
    const int rA = lane & 15;
    const int kg = lane >> 4;          // 0..3, k-group of 8

    f32x4 acc[2][8];
    #pragma unroll
    for (int m = 0; m < 2; ++m)
        #pragma unroll
        for (int nt = 0; nt < 8; ++nt)
            acc[m][nt] = (f32x4){0.f, 0.f, 0.f, 0.f};

    int ra0 = row0 + rA;        if (ra0 > NNODES - 1) ra0 = NNODES - 1;
    int ra1 = row0 + 16 + rA;   if (ra1 > NNODES - 1) ra1 = NNODES - 1;

    #pragma unroll
    for (int ks = 0; ks < 8; ++ks) {
        const _Float16* srcb = (ks < 4) ? Ah : Xh;
        const int klocal = (ks & 3) * 32 + kg * 8;
        half8_t a0 = *reinterpret_cast<const half8_t*>(&srcb[(size_t)ra0 * DIM + klocal]);
        half8_t a1 = *reinterpret_cast<const half8_t*>(&srcb[(size_t)ra1 * DIM + klocal]);
        const int kglob = ks * 32 + kg * 8;
        #pragma unroll
        for (int nt = 0; nt < 8; ++nt) {
            half8_t b = *reinterpret_cast<const half8_t*>(&WT[(size_t)(nt * 16 + rA) * 256 + kglob]);
            acc[0][nt] = __builtin_amdgcn_mfma_f32_16x16x32_f16(a0, b, acc[0][nt], 0, 0, 0);
            acc[1][nt] = __builtin_amdgcn_mfma_f32_16x16x32_f16(a1, b, acc[1][nt], 0, 0, 0);
        }
    }

    // C/D layout (HW-verified): col = lane&15, row = (lane>>4)*4 + reg
    const int ccol = lane & 15;
    const int crow4 = (lane >> 4) * 4;
    #pragma unroll
    for (int m = 0; m < 2; ++m) {
        #pragma unroll
        for (int nt = 0; nt < 8; ++nt) {
            float bb = bias[nt * 16 + ccol];
            #pragma unroll
            for (int r = 0; r < 4; ++r) {
                int row = row0 + m * 16 + crow4 + r;
                if (row < NNODES) {
                    float v = acc[m][nt][r] + bb;
                    outh[(size_t)row * DIM + nt * 16 + ccol] = (_Float16)(v > 0.f ? v : 0.f);
                }
            }
        }
    }
}

// ---------------- fused mean-pool + MLP: out[g] = relu(mean_g(h)@fc1+b1)@fc2 + b2 ----------------
__global__ void pool_mlp_kernel(const _Float16* __restrict__ h,
                                const int* __restrict__ batch,
                                const float* __restrict__ fc1_w,
                                const float* __restrict__ fc1_b,
                                const float* __restrict__ fc2_w,
                                const float* __restrict__ fc2_b,
                                float* __restrict__ out) {
    __shared__ float p[DIM];
    __shared__ float red[DIM];
    int g = blockIdx.x;
    int c = threadIdx.x;  // 0..127
    int lo = 0, hi = NNODES;
    while (lo < hi) { int m = (lo + hi) >> 1; if (batch[m] < g) lo = m + 1; else hi = m; }
    int beg = lo;
    hi = NNODES;
    while (lo < hi) { int m = (lo + hi) >> 1; if (batch[m] < g + 1) lo = m + 1; else hi = m; }
    int end = lo;
    float acc0 = 0.f, acc1 = 0.f;
    int n = beg;
    for (; n + 2 <= end; n += 2) {
        acc0 += (float)h[(size_t)n * DIM + c];
        acc1 += (float)h[(size_t)(n + 1) * DIM + c];
    }
    if (n < end) acc0 += (float)h[(size_t)n * DIM + c];
    float cnt = (float)(end - beg);
    p[c] = (acc0 + acc1) / fmaxf(cnt, 1.f);
    __syncthreads();
    float acc = fc1_b[c];
    for (int k = 0; k < DIM; ++k) acc = fmaf(p[k], fc1_w[k * DIM + c], acc);
    acc = acc > 0.f ? acc : 0.f;
    red[c] = acc * fc2_w[c];
    __syncthreads();
    #pragma unroll
    for (int s = 64; s > 0; s >>= 1) {
        if (c < s) red[c] += red[c + s];
        __syncthreads();
    }
    if (c == 0) out[g] = red[0] + fc2_b[0];
}

extern "C" void kernel_launch(void* const* d_in, const int* in_sizes, int n_in,
                              void* d_out, int out_size, void* d_ws, size_t ws_size,
                              hipStream_t stream) {
    const float* x       = (const float*)d_in[0];
    const int*   ei      = (const int*)d_in[1];
    const int*   batch   = (const int*)d_in[2];
    const float* w1_rel  = (const float*)d_in[3];
    const float* b1_rel  = (const float*)d_in[4];
    const float* w1_root = (const float*)d_in[5];
    const float* w2_rel  = (const float*)d_in[6];
    const float* b2_rel  = (const float*)d_in[7];
    const float* w2_root = (const float*)d_in[8];
    const float* fc1_w   = (const float*)d_in[9];
    const float* fc1_b   = (const float*)d_in[10];
    const float* fc2_w   = (const float*)d_in[11];
    const float* fc2_b   = (const float*)d_in[12];
    float* out = (float*)d_out;

    char* ws = (char*)d_ws;
    const size_t feath_bytes = (size_t)NNODES * DIM * sizeof(_Float16);  // 12.8 MB
    _Float16* Ah  = (_Float16*)ws;                                   // agg buffer (f16)
    _Float16* Hh  = (_Float16*)(ws + feath_bytes);                   // activations (f16)
    _Float16* xh  = (_Float16*)(ws + 2 * feath_bytes);               // x cast (f16)
    _Float16* WT1 = (_Float16*)(ws + 3 * feath_bytes);               // [128][256] f16
    _Float16* WT2 = WT1 + 128 * 256;
    int*   deg    = (int*)(WT2 + 128 * 256);       // [NPAD]
    int*   offs   = deg + NPAD;                    // [NPAD]
    int*   curs   = offs + NPAD;                   // [NPAD]
    int*   bsum   = curs + NPAD;                   // [256]
    int*   srcs   = bsum + 256;                    // [NEDGES]

    const int* src = ei;           // edge_index[0]
    const int* dst = ei + NEDGES;  // edge_index[1]

    const int edge_blocks = (NEDGES + 255) / 256;   // 3125
    const int conv_blocks = (NNODES + 127) / 128;   // 391
    const int agg_blocks  = (NNODES + 15) / 16;     // 3125

    // ---- casts ----
    cast_x_kernel<<<(NNODES * DIM / 8) / 256, 256, 0, stream>>>(x, xh);
    cast_w_kernel<<<256, 256, 0, stream>>>(w1_rel, w1_root, w2_rel, w2_root, WT1, WT2);

    // ---- build dst-sorted adjacency (once, reused by both layers) ----
    hipMemsetAsync(deg, 0, NPAD * sizeof(int), stream);
    hist_kernel<<<edge_blocks, 256, 0, stream>>>(dst, deg);
    scan1_kernel<<<SCAN_BLOCKS, 256, 0, stream>>>(deg, bsum);
    scan2_kernel<<<1, 256, 0, stream>>>(bsum);
    scan3_kernel<<<SCAN_BLOCKS, 256, 0, stream>>>(deg, bsum, offs, curs);
    bucket_kernel<<<edge_blocks, 256, 0, stream>>>(src, dst, curs, srcs);

    // ---- layer 1 ----
    gather_agg_kernel<<<agg_blocks, 256, 0, stream>>>(xh, offs, srcs, Ah);
    conv_mfma_kernel<<<conv_blocks, 256, 0, stream>>>(Ah, xh, WT1, b1_rel, Hh);

    // ---- layer 2 (in-place on Hh) ----
    gather_agg_kernel<<<agg_blocks, 256, 0, stream>>>(Hh, offs, srcs, Ah);
    conv_mfma_kernel<<<conv_blocks, 256, 0, stream>>>(Ah, Hh, WT2, b2_rel, Hh);

    // ---- fused pool + MLP ----
    pool_mlp_kernel<<<NGRAPHS, 128, 0, stream>>>(Hh, batch, fc1_w, fc1_b, fc2_w, fc2_b, out);
}

// Round 13
// 324.272 us; speedup vs baseline: 9.9334x; 1.0691x over previous
//
#include <hip/hip_runtime.h>

#define NNODES 50000
#define NEDGES 800000
#define DIM 128
#define NGRAPHS 256
#define NPAD 50176      // 196*256, padded node count for int arrays
#define SCAN_BLOCKS 196
#define NXCD 8
#define NODES_PER_XCD (NNODES / NXCD)   // 6250
#define GB 391                           // blocks per XCD group
#define EPB 2048                         // edges per block chunk (256 thr x 8)

typedef _Float16 half8_t __attribute__((ext_vector_type(8)));
typedef float f32x4 __attribute__((ext_vector_type(4)));

// ---------------- fused prep: cast x->f16, build WT1/WT2, XCD-local histogram ----------------
// grid = GB*NXCD = 3128 blocks x 256.
__global__ void prep_kernel(const float* __restrict__ x, _Float16* __restrict__ xh,
                            const float* __restrict__ w1_rel, const float* __restrict__ w1_root,
                            const float* __restrict__ w2_rel, const float* __restrict__ w2_root,
                            _Float16* __restrict__ WT1, _Float16* __restrict__ WT2,
                            const int* __restrict__ dst, int* __restrict__ deg) {
    int tid = blockIdx.x * 256 + threadIdx.x;

    // ---- cast x (8 f32 -> 8 f16 per thread), t < 800000 ----
    if (tid < (NNODES * DIM / 8)) {
        const float4* x4 = reinterpret_cast<const float4*>(x);
        float4 a = x4[tid * 2];
        float4 b = x4[tid * 2 + 1];
        half8_t h;
        h[0] = (_Float16)a.x; h[1] = (_Float16)a.y; h[2] = (_Float16)a.z; h[3] = (_Float16)a.w;
        h[4] = (_Float16)b.x; h[5] = (_Float16)b.y; h[6] = (_Float16)b.z; h[7] = (_Float16)b.w;
        *reinterpret_cast<half8_t*>(&xh[(size_t)tid * 8]) = h;
    }

    // ---- cast/transpose weights, t < 65536 ----
    if (tid < 2 * DIM * 256) {
        int layer = tid >> 15;
        int r = tid & 32767;
        int c = r >> 8;        // 0..127 output col
        int k = r & 255;       // 0..255 combined K
        const float* wr = layer ? w2_rel : w1_rel;
        const float* wo = layer ? w2_root : w1_root;
        float v = (k < 128) ? wr[k * DIM + c] : wo[(k - 128) * DIM + c];
        _Float16* dstp = layer ? WT2 : WT1;
        dstp[(size_t)c * 256 + k] = (_Float16)v;
    }

    // ---- XCD-local histogram: group g commits only dst in [g*6250,(g+1)*6250) ----
    int g  = blockIdx.x & (NXCD - 1);
    int bb = blockIdx.x >> 3;
    int lo = g * NODES_PER_XCD, hi = lo + NODES_PER_XCD;
    int base = bb * EPB + threadIdx.x;
    #pragma unroll
    for (int i = 0; i < 8; ++i) {
        int e = base + i * 256;
        if (e < NEDGES) {
            int d = dst[e];
            if (d >= lo && d < hi) atomicAdd(&deg[d], 1);
        }
    }
}

// ---------------- 3-phase exclusive scan over deg[NPAD] ----------------
__global__ void scan1_kernel(const int* __restrict__ deg, int* __restrict__ bsum) {
    __shared__ int s[256];
    int t = threadIdx.x;
    s[t] = deg[blockIdx.x * 256 + t];
    __syncthreads();
    #pragma unroll
    for (int d = 128; d > 0; d >>= 1) {
        if (t < d) s[t] += s[t + d];
        __syncthreads();
    }
    if (t == 0) bsum[blockIdx.x] = s[0];
}

__global__ void scan2_kernel(int* __restrict__ bsum) {
    __shared__ int s[256];
    int t = threadIdx.x;
    int v = (t < SCAN_BLOCKS) ? bsum[t] : 0;
    s[t] = v;
    __syncthreads();
    #pragma unroll
    for (int d = 1; d < 256; d <<= 1) {
        int u = (t >= d) ? s[t - d] : 0;
        __syncthreads();
        s[t] += u;
        __syncthreads();
    }
    if (t < SCAN_BLOCKS) bsum[t] = (t == 0) ? 0 : s[t - 1];
}

__global__ void scan3_kernel(const int* __restrict__ deg,
                             const int* __restrict__ bsum,
                             int* __restrict__ offs,
                             int* __restrict__ curs) {
    __shared__ int s[256];
    int t = threadIdx.x;
    int idx = blockIdx.x * 256 + t;
    s[t] = deg[idx];
    __syncthreads();
    #pragma unroll
    for (int d = 1; d < 256; d <<= 1) {
        int u = (t >= d) ? s[t - d] : 0;
        __syncthreads();
        s[t] += u;
        __syncthreads();
    }
    int excl = ((t == 0) ? 0 : s[t - 1]) + bsum[blockIdx.x];
    if (idx <= NNODES) {
        offs[idx] = excl;
        curs[idx] = excl;
    }
}

// ---------------- bucket edges by dst, XCD-localized ----------------
// group g (= blockIdx%8, lands on XCD g) commits only its dst-range: CSR lines
// and curs counters for that range stay in ONE XCD's L2 -> single full-line
// eviction instead of 8-way partial-line churn.
__global__ void bucket_kernel(const int* __restrict__ src,
                              const int* __restrict__ dst,
                              int* __restrict__ curs,
                              int* __restrict__ srcs_sorted) {
    int g  = blockIdx.x & (NXCD - 1);
    int bb = blockIdx.x >> 3;
    int lo = g * NODES_PER_XCD, hi = lo + NODES_PER_XCD;
    int base = bb * EPB + threadIdx.x;
    #pragma unroll
    for (int i = 0; i < 8; ++i) {
        int e = base + i * 256;
        if (e < NEDGES) {
            int d = dst[e];
            if (d >= lo && d < hi) {
                int pos = atomicAdd(&curs[d], 1);
                srcs_sorted[pos] = src[e];
            }
        }
    }
}

// ---------------- gather-aggregate (f16 in, f16 out, f32 accum) ----------------
// 16 lanes per node (half8 = 16B each), 16 nodes per 256-thread block.
// 4-deep neighbor unroll for ILP. No atomics.
__global__ void gather_agg_kernel(const _Float16* __restrict__ feat,
                                  const int* __restrict__ offs,
                                  const int* __restrict__ srcs_sorted,
                                  _Float16* __restrict__ agg) {
    int n = blockIdx.x * 16 + (threadIdx.x >> 4);
    int q = threadIdx.x & 15;
    if (n >= NNODES) return;
    int beg = offs[n], end = offs[n + 1];
    float a0[8] = {0.f, 0.f, 0.f, 0.f, 0.f, 0.f, 0.f, 0.f};
    float a1[8] = {0.f, 0.f, 0.f, 0.f, 0.f, 0.f, 0.f, 0.f};
    int i = beg;
    for (; i + 4 <= end; i += 4) {
        int s0 = srcs_sorted[i + 0];
        int s1 = srcs_sorted[i + 1];
        int s2 = srcs_sorted[i + 2];
        int s3 = srcs_sorted[i + 3];
        half8_t v0 = *reinterpret_cast<const half8_t*>(&feat[(size_t)s0 * DIM + q * 8]);
        half8_t v1 = *reinterpret_cast<const half8_t*>(&feat[(size_t)s1 * DIM + q * 8]);
        half8_t v2 = *reinterpret_cast<const half8_t*>(&feat[(size_t)s2 * DIM + q * 8]);
        half8_t v3 = *reinterpret_cast<const half8_t*>(&feat[(size_t)s3 * DIM + q * 8]);
        #pragma unroll
        for (int j = 0; j < 8; ++j) {
            a0[j] += (float)v0[j] + (float)v1[j];
            a1[j] += (float)v2[j] + (float)v3[j];
        }
    }
    for (; i < end; ++i) {
        half8_t v = *reinterpret_cast<const half8_t*>(&feat[(size_t)srcs_sorted[i] * DIM + q * 8]);
        #pragma unroll
        for (int j = 0; j < 8; ++j) a0[j] += (float)v[j];
    }
    half8_t r;
    #pragma unroll
    for (int j = 0; j < 8; ++j) r[j] = (_Float16)(a0[j] + a1[j]);
    *reinterpret_cast<half8_t*>(&agg[(size_t)n * DIM + q * 8]) = r;
}

// ------------- GraphConv dense part via fp16 MFMA -------------
// out = relu([Ah|Xh] @ WT^T + b), K=256 combined. Block = 4 waves = 128 rows.
// Per wave: 32 rows x 128 cols = 2 Msub x 8 Ntiles of 16x16x32 MFMA, f32 accum.
// No LDS: A/B frags via L1/L2. Xh/outh may alias (layer2 in-place): each block
// reads only its own rows and all reads precede its writes.
__global__ __launch_bounds__(256) void conv_mfma_kernel(
        const _Float16* __restrict__ Ah,
        const _Float16* Xh,
        const _Float16* __restrict__ WT,   // [128 cols][256 k]
        const float* __restrict__ bias,    // [128]
        _Float16* outh) {
    const int wave = threadIdx.x >> 6;
    const int lane = threadIdx.x & 63;
    const int row0 = blockIdx.x * 128 + wave * 32;
    const int rA = lane & 15;
    const int kg = lane >> 4;          // 0..3, k-group of 8

    f32x4 acc[2][8];
    #pragma unroll
    for (int m = 0; m < 2; ++m)
        #pragma unroll
        for (int nt = 0; nt < 8; ++nt)
            acc[m][nt] = (f32x4){0.f, 0.f, 0.f, 0.f};

    int ra0 = row0 + rA;        if (ra0 > NNODES - 1) ra0 = NNODES - 1;
    int ra1 = row0 + 16 + rA;   if (ra1 > NNODES - 1) ra1 = NNODES - 1;

    #pragma unroll
    for (int ks = 0; ks < 8; ++ks) {
        const _Float16* srcb = (ks < 4) ? Ah : Xh;
        const int klocal = (ks & 3) * 32 + kg * 8;
        half8_t a0 = *reinterpret_cast<const half8_t*>(&srcb[(size_t)ra0 * DIM + klocal]);
        half8_t a1 = *reinterpret_cast<const half8_t*>(&srcb[(size_t)ra1 * DIM + klocal]);
        const int kglob = ks * 32 + kg * 8;
        #pragma unroll
        for (int nt = 0; nt < 8; ++nt) {
            half8_t b = *reinterpret_cast<const half8_t*>(&WT[(size_t)(nt * 16 + rA) * 256 + kglob]);
            acc[0][nt] = __builtin_amdgcn_mfma_f32_16x16x32_f16(a0, b, acc[0][nt], 0, 0, 0);
            acc[1][nt] = __builtin_amdgcn_mfma_f32_16x16x32_f16(a1, b, acc[1][nt], 0, 0, 0);
        }
    }

    // C/D layout (HW-verified): col = lane&15, row = (lane>>4)*4 + reg
    const int ccol = lane & 15;
    const int crow4 = (lane >> 4) * 4;
    #pragma unroll
    for (int m = 0; m < 2; ++m) {
        #pragma unroll
        for (int nt = 0; nt < 8; ++nt) {
            float bb = bias[nt * 16 + ccol];
            #pragma unroll
            for (int r = 0; r < 4; ++r) {
                int row = row0 + m * 16 + crow4 + r;
                if (row < NNODES) {
                    float v = acc[m][nt][r] + bb;
                    outh[(size_t)row * DIM + nt * 16 + ccol] = (_Float16)(v > 0.f ? v : 0.f);
                }
            }
        }
    }
}

// ---------------- fused mean-pool + MLP: out[g] = relu(mean_g(h)@fc1+b1)@fc2 + b2 ----------------
__global__ void pool_mlp_kernel(const _Float16* __restrict__ h,
                                const int* __restrict__ batch,
                                const float* __restrict__ fc1_w,
                                const float* __restrict__ fc1_b,
                                const float* __restrict__ fc2_w,
                                const float* __restrict__ fc2_b,
                                float* __restrict__ out) {
    __shared__ float p[DIM];
    __shared__ float red[DIM];
    int g = blockIdx.x;
    int c = threadIdx.x;  // 0..127
    int lo = 0, hi = NNODES;
    while (lo < hi) { int m = (lo + hi) >> 1; if (batch[m] < g) lo = m + 1; else hi = m; }
    int beg = lo;
    hi = NNODES;
    while (lo < hi) { int m = (lo + hi) >> 1; if (batch[m] < g + 1) lo = m + 1; else hi = m; }
    int end = lo;
    float acc0 = 0.f, acc1 = 0.f;
    int n = beg;
    for (; n + 2 <= end; n += 2) {
        acc0 += (float)h[(size_t)n * DIM + c];
        acc1 += (float)h[(size_t)(n + 1) * DIM + c];
    }
    if (n < end) acc0 += (float)h[(size_t)n * DIM + c];
    float cnt = (float)(end - beg);
    p[c] = (acc0 + acc1) / fmaxf(cnt, 1.f);
    __syncthreads();
    float acc = fc1_b[c];
    for (int k = 0; k < DIM; ++k) acc = fmaf(p[k], fc1_w[k * DIM + c], acc);
    acc = acc > 0.f ? acc : 0.f;
    red[c] = acc * fc2_w[c];
    __syncthreads();
    #pragma unroll
    for (int s = 64; s > 0; s >>= 1) {
        if (c < s) red[c] += red[c + s];
        __syncthreads();
    }
    if (c == 0) out[g] = red[0] + fc2_b[0];
}

extern "C" void kernel_launch(void* const* d_in, const int* in_sizes, int n_in,
                              void* d_out, int out_size, void* d_ws, size_t ws_size,
                              hipStream_t stream) {
    const float* x       = (const float*)d_in[0];
    const int*   ei      = (const int*)d_in[1];
    const int*   batch   = (const int*)d_in[2];
    const float* w1_rel  = (const float*)d_in[3];
    const float* b1_rel  = (const float*)d_in[4];
    const float* w1_root = (const float*)d_in[5];
    const float* w2_rel  = (const float*)d_in[6];
    const float* b2_rel  = (const float*)d_in[7];
    const float* w2_root = (const float*)d_in[8];
    const float* fc1_w   = (const float*)d_in[9];
    const float* fc1_b   = (const float*)d_in[10];
    const float* fc2_w   = (const float*)d_in[11];
    const float* fc2_b   = (const float*)d_in[12];
    float* out = (float*)d_out;

    char* ws = (char*)d_ws;
    const size_t feath_bytes = (size_t)NNODES * DIM * sizeof(_Float16);  // 12.8 MB
    _Float16* Ah  = (_Float16*)ws;                                   // agg buffer (f16)
    _Float16* Hh  = (_Float16*)(ws + feath_bytes);                   // activations (f16)
    _Float16* xh  = (_Float16*)(ws + 2 * feath_bytes);               // x cast (f16)
    _Float16* WT1 = (_Float16*)(ws + 3 * feath_bytes);               // [128][256] f16
    _Float16* WT2 = WT1 + 128 * 256;
    int*   deg    = (int*)(WT2 + 128 * 256);       // [NPAD]
    int*   offs   = deg + NPAD;                    // [NPAD]
    int*   curs   = offs + NPAD;                   // [NPAD]
    int*   bsum   = curs + NPAD;                   // [256]
    int*   srcs   = bsum + 256;                    // [NEDGES]

    const int* src = ei;           // edge_index[0]
    const int* dst = ei + NEDGES;  // edge_index[1]

    const int xcd_blocks  = GB * NXCD;              // 3128
    const int conv_blocks = (NNODES + 127) / 128;   // 391
    const int agg_blocks  = (NNODES + 15) / 16;     // 3125

    // ---- prep: casts + XCD-local histogram (deg must be zeroed first) ----
    hipMemsetAsync(deg, 0, NPAD * sizeof(int), stream);
    prep_kernel<<<xcd_blocks, 256, 0, stream>>>(x, xh, w1_rel, w1_root, w2_rel, w2_root,
                                                WT1, WT2, dst, deg);

    // ---- CSR offsets + XCD-localized bucket scatter ----
    scan1_kernel<<<SCAN_BLOCKS, 256, 0, stream>>>(deg, bsum);
    scan2_kernel<<<1, 256, 0, stream>>>(bsum);
    scan3_kernel<<<SCAN_BLOCKS, 256, 0, stream>>>(deg, bsum, offs, curs);
    bucket_kernel<<<xcd_blocks, 256, 0, stream>>>(src, dst, curs, srcs);

    // ---- layer 1 ----
    gather_agg_kernel<<<agg_blocks, 256, 0, stream>>>(xh, offs, srcs, Ah);
    conv_mfma_kernel<<<conv_blocks, 256, 0, stream>>>(Ah, xh, WT1, b1_rel, Hh);

    // ---- layer 2 (in-place on Hh) ----
    gather_agg_kernel<<<agg_blocks, 256, 0, stream>>>(Hh, offs, srcs, Ah);
    conv_mfma_kernel<<<conv_blocks, 256, 0, stream>>>(Ah, Hh, WT2, b2_rel, Hh);

    // ---- fused pool + MLP ----
    pool_mlp_kernel<<<NGRAPHS, 128, 0, stream>>>(Hh, batch, fc1_w, fc1_b, fc2_w, fc2_b, out);
}